// Round 9
// baseline (585.968 us; speedup 1.0000x reference)
//
#include <hip/hip_runtime.h>
#include <math.h>

// ---------------------------------------------------------------------------
// N2V GCN edge model, fp32.
//   CSR build: cnt=indeg(dst); dinv=rsqrt(cnt+1); rp=exscan; srcs+coefs bucketed
//   L1: A = x@W1 ; B = relu(gatherCSR(A) + A*dinv^2 + b1)
//   L2: A = B@W2 ; B = relu(gatherCSR(A) + A*dinv^2 + b2)
//   head: per pair: feat=[u,v,|u-v|,u*v]; z=relu(feat@M1+mb1); out=z@M2+mb2
// Round-9: head reads M1 from LDS instead of per-t s_load bursts.
//   r8 showed the head is not traffic-bound (FETCH 177->107MB, time flat);
//   the stall is the per-t 32-float scalar M1 burst: only ~1 iter of SGPR
//   prefetch headroom, and s_load shares lgkmcnt with ds_read -> coarse
//   waits expose SMEM latency every t. Now each phase cooperatively stages
//   its 16-row M1 slice (16KB, coalesced, L2-hot) and the inner loop reads
//   it via wave-uniform ds_read_b128 (broadcast). Zero s_loads in the loop.
//   LDS 48KB -> 3 blocks/CU (launch_bounds(512,6)).
// ---------------------------------------------------------------------------

__global__ void k_count_int(const int* __restrict__ dst, int* __restrict__ cnt, int e) {
  int i = blockIdx.x * blockDim.x + threadIdx.x;
  if (i < e) atomicAdd(&cnt[dst[i]], 1);
}

__global__ void k_dinv(const int* __restrict__ cnt, float* __restrict__ dinv, int n) {
  int i = blockIdx.x * blockDim.x + threadIdx.x;
  if (i < n) dinv[i] = rsqrtf((float)cnt[i] + 1.0f);  // self-loop included
}

__global__ __launch_bounds__(256) void k_scan_block(const int* __restrict__ cnt,
                                                    int* __restrict__ rp,
                                                    int* __restrict__ bsum, int n) {
  __shared__ int wsum[4];
  int tid = threadIdx.x;
  int lane = tid & 63, w = tid >> 6;
  int idx = blockIdx.x * 1024 + tid * 4;
  int v0 = (idx + 0 < n) ? cnt[idx + 0] : 0;
  int v1 = (idx + 1 < n) ? cnt[idx + 1] : 0;
  int v2 = (idx + 2 < n) ? cnt[idx + 2] : 0;
  int v3 = (idx + 3 < n) ? cnt[idx + 3] : 0;
  int tot = v0 + v1 + v2 + v3;
  int x = tot;
#pragma unroll
  for (int off = 1; off < 64; off <<= 1) {
    int y = __shfl_up(x, off, 64);
    if (lane >= off) x += y;
  }
  if (lane == 63) wsum[w] = x;
  __syncthreads();
  int woff = 0;
  for (int i = 0; i < w; ++i) woff += wsum[i];
  int run = woff + x - tot;
  if (idx + 0 < n) rp[idx + 0] = run; run += v0;
  if (idx + 1 < n) rp[idx + 1] = run; run += v1;
  if (idx + 2 < n) rp[idx + 2] = run; run += v2;
  if (idx + 3 < n) rp[idx + 3] = run;
  if (tid == 255) bsum[blockIdx.x] = wsum[0] + wsum[1] + wsum[2] + wsum[3];
}

__global__ void k_scan_bsum(int* __restrict__ bsum, int nb) {
  int l = threadIdx.x;
  int v0 = (l < nb) ? bsum[l] : 0;
  int v1 = (64 + l < nb) ? bsum[64 + l] : 0;
  int i0 = v0;
#pragma unroll
  for (int off = 1; off < 64; off <<= 1) {
    int y = __shfl_up(i0, off, 64);
    if (l >= off) i0 += y;
  }
  int T0 = __shfl(i0, 63, 64);
  int i1 = v1;
#pragma unroll
  for (int off = 1; off < 64; off <<= 1) {
    int y = __shfl_up(i1, off, 64);
    if (l >= off) i1 += y;
  }
  if (l < nb) bsum[l] = i0 - v0;
  if (64 + l < nb) bsum[64 + l] = T0 + i1 - v1;
}

// add block offsets; also emit cursor copy for k_fill; set rp[n]=E.
__global__ void k_scan_add(int* __restrict__ rp, int* __restrict__ cur,
                           const int* __restrict__ bsum, int n, int e) {
  int i = blockIdx.x * blockDim.x + threadIdx.x;
  if (i < n) {
    int v = rp[i] + bsum[i >> 10];
    rp[i] = v;
    cur[i] = v;
  }
  if (i == 0) rp[n] = e;
}

// fill CSR buckets; also precompute per-edge coefficient.
__global__ void k_fill(const int* __restrict__ src, const int* __restrict__ dst,
                       int* __restrict__ cur, const float* __restrict__ dinv,
                       int* __restrict__ srcs, float* __restrict__ coefs, int e) {
  int i = blockIdx.x * blockDim.x + threadIdx.x;
  if (i >= e) return;
  int s = src[i], d = dst[i];
  int pos = atomicAdd(&cur[d], 1);
  srcs[pos] = s;
  coefs[pos] = dinv[s] * dinv[d];
}

// ---------------------------------------------------------------------------
// Matmul, W-in-VGPR: OUT[node][lane] = sum_k IN[node][k]*W[k][lane].
// ---------------------------------------------------------------------------
template <int K>
__global__ __launch_bounds__(256) void k_matmul_w(const float* __restrict__ IN,
                                                  const float* __restrict__ W,
                                                  float* __restrict__ OUT,
                                                  int n, int npw) {
  __shared__ float rows[4][K];
  const int wv = threadIdx.x >> 6, lane = threadIdx.x & 63;
  float wreg[K];
#pragma unroll
  for (int k = 0; k < K; ++k) wreg[k] = W[k * 64 + lane];
  int base = (blockIdx.x * 4 + wv) * npw;
  if (base >= n) return;
  int nEnd = base + npw;
  if (nEnd > n) nEnd = n;
  float p0 = IN[(size_t)base * K + lane];
  float p1 = (K == 128) ? IN[(size_t)base * K + 64 + lane] : 0.f;
  for (int node = base; node < nEnd; ++node) {
    rows[wv][lane] = p0;
    if (K == 128) rows[wv][64 + lane] = p1;
    if (node + 1 < nEnd) {  // prefetch next row under this node's compute
      p0 = IN[(size_t)(node + 1) * K + lane];
      if (K == 128) p1 = IN[(size_t)(node + 1) * K + 64 + lane];
    }
    float a0 = 0.f, a1 = 0.f, a2 = 0.f, a3 = 0.f;
#pragma unroll
    for (int k = 0; k < K; k += 4) {
      float4 xk = *(const float4*)&rows[wv][k];
      a0 = fmaf(xk.x, wreg[k + 0], a0);
      a1 = fmaf(xk.y, wreg[k + 1], a1);
      a2 = fmaf(xk.z, wreg[k + 2], a2);
      a3 = fmaf(xk.w, wreg[k + 3], a3);
    }
    OUT[(size_t)node * 64 + lane] = (a0 + a1) + (a2 + a3);
  }
}

// one wave per node; wave-uniform shfl-broadcast accumulate; coalesced
// srcs/coefs streams (coefs precomputed in k_fill).
__global__ void k_gather(const float* __restrict__ hlin, const int* __restrict__ rp,
                         const int* __restrict__ srcs, const float* __restrict__ coefs,
                         const float* __restrict__ dinv,
                         const float* __restrict__ bias, float* __restrict__ outB,
                         int n) {
  int warp = threadIdx.x >> 6, lane = threadIdx.x & 63;
  int node = blockIdx.x * 4 + warp;
  if (node >= n) return;
  int g = lane >> 4, l16 = lane & 15;
  int beg = rp[node], end = rp[node + 1];
  int deg = end - beg;
  float dn = dinv[node];
  float ax = 0.f, ay = 0.f, az = 0.f, aw = 0.f;
  for (int base = 0; base < deg; base += 64) {
    int rem = deg - base;
    int m = rem < 64 ? rem : 64;
    int idx = 0;
    float cf = 0.f;
    if (lane < m) {
      idx = srcs[beg + base + lane];
      cf = coefs[beg + base + lane];
    }
    int iters = (m + 3) >> 2;  // wave-uniform trip count
    for (int i = 0; i < iters; ++i) {
      int k = g + 4 * i;  // <= 63 always; k>=m harmless (cf=0)
      int s = __shfl(idx, k, 64);
      float c = __shfl(cf, k, 64);
      float4 h = *(const float4*)(hlin + (size_t)s * 64 + l16 * 4);
      ax = fmaf(h.x, c, ax);
      ay = fmaf(h.y, c, ay);
      az = fmaf(h.z, c, az);
      aw = fmaf(h.w, c, aw);
    }
  }
#pragma unroll
  for (int off = 16; off < 64; off <<= 1) {
    ax += __shfl_xor(ax, off, 64);
    ay += __shfl_xor(ay, off, 64);
    az += __shfl_xor(az, off, 64);
    aw += __shfl_xor(aw, off, 64);
  }
  if (g == 0) {
    float4 hs = *(const float4*)(hlin + (size_t)node * 64 + l16 * 4);
    float4 bb = *(const float4*)(bias + l16 * 4);
    float dd = dn * dn;
    float4 o;
    o.x = ax + hs.x * dd + bb.x;
    o.y = ay + hs.y * dd + bb.y;
    o.z = az + hs.z * dd + bb.z;
    o.w = aw + hs.w * dd + bb.w;
    o.x = o.x > 0.f ? o.x : 0.f;
    o.y = o.y > 0.f ? o.y : 0.f;
    o.z = o.z > 0.f ? o.z : 0.f;
    o.w = o.w > 0.f ? o.w : 0.f;
    *(float4*)(outB + (size_t)node * 64 + l16 * 4) = o;
  }
}

// ---------------------------------------------------------------------------
// Edge head: 512 threads = 8 waves, 256 pairs/block, 4 pairs/lane.
// Wave w owns cols [8w, 8w+8); lane owns pairs 4*lane..4*lane+3.
// 4 phases x 16 rows. LDS: u[16][256] + v[16][256] (32KB, parts reuse u) +
// m1s[4][16][64] (16KB, this phase's M1 slice) = 48KB -> 3 blocks/CU.
// u/v staged at 128B-line granularity (even phase loads full line, odd phase
// writes the reg stash). M1 slice staged coalesced each phase; inner-loop M1
// reads are wave-uniform ds_read_b128 broadcasts -> no s_loads in the loop.
// ---------------------------------------------------------------------------
__global__ __launch_bounds__(512, 6) void k_edge_head(
    const float* __restrict__ H, const int* __restrict__ ep,
    const float* __restrict__ M1, const float* __restrict__ mb1,
    const float* __restrict__ M2, const float* __restrict__ mb2,
    float* __restrict__ out, int p_total) {
  __shared__ float sbuf[8192];   // u:[0,4096) v:[4096,8192); parts reuse u
  __shared__ float m1s[4096];    // [blk][t][col] = [4][16][64], phase slice

  const int tid = threadIdx.x;
  const int pair0 = blockIdx.x * 256;

  // staging identity: thread handles u (hf=0) or v (hf=1) of pair pi
  const int pi = tid & 255;
  const int hf = tid >> 8;
  const int gp_pi = pair0 + pi;
  const bool valid = gp_pi < p_total;
  int node = 0;
  if (valid) node = hf ? ep[p_total + gp_pi] : ep[gp_pi];
  float* __restrict__ myb = sbuf + hf * 4096;

  // gemm identity
  const int lane = tid & 63;
  const int w = tid >> 6;  // 0..7
  const int cg = __builtin_amdgcn_readfirstlane(w);
  const int p0 = 4 * lane;

  const float4* M1_4 = (const float4*)M1;
  float4* m1s4w = (float4*)m1s;
  const float4* m1s4 = (const float4*)m1s;

  float acc[8][4];
#pragma unroll
  for (int c = 0; c < 8; ++c)
#pragma unroll
    for (int p = 0; p < 4; ++p) acc[c][p] = 0.f;

  float4 st0, st1, st2, st3;  // stash: next phase's 16 rows (64B)

#pragma unroll
  for (int ph = 0; ph < 4; ++ph) {
    if (ph) __syncthreads();  // previous phase fully consumed

    // ---- stage this phase's M1 slice: 1024 float4, 2 per thread, coalesced.
    // m1s flat f -> blk=f>>8 (in float4 rows of 16), within = f&255;
    // global float4 idx = blk*1024 + ph*256 + (f&255).
    {
      int f = tid * 2;
      m1s4w[f]     = M1_4[(f >> 8) * 1024 + ph * 256 + (f & 255)];
      m1s4w[f + 1] = M1_4[((f + 1) >> 8) * 1024 + ph * 256 + ((f + 1) & 255)];
    }

    // ---- stage 16 rows of this thread's matrix (u or v), pair pi
    if (valid) {
      float4 c0, c1, c2, c3;
      if ((ph & 1) == 0) {
        // even phase: read the full 128B line (this phase + next phase)
        const float4* hr = (const float4*)(H + (size_t)node * 64 + ph * 16);
        c0 = hr[0]; c1 = hr[1]; c2 = hr[2]; c3 = hr[3];
        st0 = hr[4]; st1 = hr[5]; st2 = hr[6]; st3 = hr[7];
      } else {
        // odd phase: no global loads, use the stash
        c0 = st0; c1 = st1; c2 = st2; c3 = st3;
      }
      myb[0 * 256 + pi]  = c0.x; myb[1 * 256 + pi]  = c0.y;
      myb[2 * 256 + pi]  = c0.z; myb[3 * 256 + pi]  = c0.w;
      myb[4 * 256 + pi]  = c1.x; myb[5 * 256 + pi]  = c1.y;
      myb[6 * 256 + pi]  = c1.z; myb[7 * 256 + pi]  = c1.w;
      myb[8 * 256 + pi]  = c2.x; myb[9 * 256 + pi]  = c2.y;
      myb[10 * 256 + pi] = c2.z; myb[11 * 256 + pi] = c2.w;
      myb[12 * 256 + pi] = c3.x; myb[13 * 256 + pi] = c3.y;
      myb[14 * 256 + pi] = c3.z; myb[15 * 256 + pi] = c3.w;
    } else {
#pragma unroll
      for (int j = 0; j < 16; ++j) myb[j * 256 + pi] = 0.f;
    }
    __syncthreads();

    // ---- GEMM over this phase's 16 feature rows (M1 from LDS broadcast)
    for (int t = 0; t < 16; ++t) {
      float4 u4 = *(const float4*)&sbuf[t * 256 + p0];
      float4 v4 = *(const float4*)&sbuf[4096 + t * 256 + p0];
      float uu[4] = {u4.x, u4.y, u4.z, u4.w};
      float vv[4] = {v4.x, v4.y, v4.z, v4.w};
      float dd[4], mm[4];
#pragma unroll
      for (int p = 0; p < 4; ++p) {
        dd[p] = fabsf(uu[p] - vv[p]);
        mm[p] = uu[p] * vv[p];
      }
      // M1 rows for this t, this wave's 8 cols: wave-uniform addresses.
      float w0c[8], w1c[8], w2c[8], w3c[8];
      *(float4*)&w0c[0] = m1s4[t * 16 + cg * 2];
      *(float4*)&w0c[4] = m1s4[t * 16 + cg * 2 + 1];
      *(float4*)&w1c[0] = m1s4[256 + t * 16 + cg * 2];
      *(float4*)&w1c[4] = m1s4[256 + t * 16 + cg * 2 + 1];
      *(float4*)&w2c[0] = m1s4[512 + t * 16 + cg * 2];
      *(float4*)&w2c[4] = m1s4[512 + t * 16 + cg * 2 + 1];
      *(float4*)&w3c[0] = m1s4[768 + t * 16 + cg * 2];
      *(float4*)&w3c[4] = m1s4[768 + t * 16 + cg * 2 + 1];
#pragma unroll
      for (int c = 0; c < 8; ++c) {
        float w0 = w0c[c], w1 = w1c[c], w2 = w2c[c], w3 = w3c[c];
#pragma unroll
        for (int p = 0; p < 4; ++p) {
          acc[c][p] = fmaf(uu[p], w0, acc[c][p]);
          acc[c][p] = fmaf(vv[p], w1, acc[c][p]);
          acc[c][p] = fmaf(dd[p], w2, acc[c][p]);
          acc[c][p] = fmaf(mm[p], w3, acc[c][p]);
        }
      }
    }
  }

  __syncthreads();  // all reads of sbuf done; reuse u region for partials

  // epilogue: per pair p: part = sum_c relu(acc+mb1)*M2 over this wave's 8 cols
#pragma unroll
  for (int p = 0; p < 4; ++p) {
    float part = 0.f;
#pragma unroll
    for (int c = 0; c < 8; ++c) {
      float z = acc[c][p] + mb1[cg * 8 + c];
      z = z > 0.f ? z : 0.f;
      part = fmaf(z, M2[cg * 8 + c], part);
    }
    sbuf[w * 256 + p0 + p] = part;
  }
  __syncthreads();

  if (tid < 256) {
    int gp = pair0 + tid;
    if (gp < p_total) {
      float s = 0.f;
#pragma unroll
      for (int w8 = 0; w8 < 8; ++w8) s += sbuf[w8 * 256 + tid];
      out[gp] = s + mb2[0];
    }
  }
}

extern "C" void kernel_launch(void* const* d_in, const int* in_sizes, int n_in,
                              void* d_out, int out_size, void* d_ws, size_t ws_size,
                              hipStream_t stream) {
  const float* x   = (const float*)d_in[0];
  const int*   gei = (const int*)d_in[1];
  const int*   ep  = (const int*)d_in[2];
  const float* W1  = (const float*)d_in[3];
  const float* b1  = (const float*)d_in[4];
  const float* W2  = (const float*)d_in[5];
  const float* b2  = (const float*)d_in[6];
  const float* M1  = (const float*)d_in[7];
  const float* mb1 = (const float*)d_in[8];
  const float* M2  = (const float*)d_in[9];
  const float* mb2 = (const float*)d_in[10];
  float* out = (float*)d_out;

  const int N = in_sizes[0] / 128;
  const int E = in_sizes[1] / 2;
  const int P = in_sizes[2] / 2;
  const int* src = gei;
  const int* dst = gei + E;

  char* ws = (char*)d_ws;
  auto align256 = [](size_t b) { return (b + 255) & ~(size_t)255; };
  size_t degBytes  = align256((size_t)N * 4);
  size_t hBytes    = align256((size_t)N * 64 * 4);
  size_t cntBytes  = align256((size_t)N * 4);
  size_t rpBytes   = align256((size_t)(N + 1) * 4);
  size_t srcBytes  = align256((size_t)E * 4);

  size_t off = 0;
  float* dinv  = (float*)(ws + off); off += degBytes;
  float* A     = (float*)(ws + off); off += hBytes;    // N x 64 (hlin)
  float* B     = (float*)(ws + off); off += hBytes;    // N x 64 (h out)
  int*   cnt   = (int*)(ws + off);   off += cntBytes;  // counts -> cursors
  int*   rp    = (int*)(ws + off);   off += rpBytes;   // N+1
  int*   srcs  = (int*)(ws + off);   off += srcBytes;  // E
  float* coefs = (float*)(ws + off); off += srcBytes;  // E
  int*   bsum  = (int*)(ws + off);                     // 128

  const int BLK = 256;
  const int nb = (N + 1023) / 1024;  // scan blocks; <=128 supported (N<=131072)

  // ---- CSR build + normalization ----
  hipMemsetAsync(cnt, 0, (size_t)N * 4, stream);
  k_count_int<<<(E + BLK - 1) / BLK, BLK, 0, stream>>>(dst, cnt, E);
  k_dinv<<<(N + BLK - 1) / BLK, BLK, 0, stream>>>(cnt, dinv, N);
  k_scan_block<<<nb, BLK, 0, stream>>>(cnt, rp, bsum, N);
  k_scan_bsum<<<1, 64, 0, stream>>>(bsum, nb);
  k_scan_add<<<(N + BLK - 1) / BLK, BLK, 0, stream>>>(rp, cnt, bsum, N, E);
  k_fill<<<(E + BLK - 1) / BLK, BLK, 0, stream>>>(src, dst, cnt, dinv, srcs, coefs, E);

  const int NPW = 16;  // nodes per wave in k_matmul_w
  const int mmGrid = (N + 4 * NPW - 1) / (4 * NPW);

  // ---- layer 1 ----
  k_matmul_w<128><<<mmGrid, BLK, 0, stream>>>(x, W1, A, N, NPW);
  k_gather<<<(N + 3) / 4, BLK, 0, stream>>>(A, rp, srcs, coefs, dinv, b1, B, N);

  // ---- layer 2 ----
  k_matmul_w<64><<<mmGrid, BLK, 0, stream>>>(B, W2, A, N, NPW);
  k_gather<<<(N + 3) / 4, BLK, 0, stream>>>(A, rp, srcs, coefs, dinv, b2, B, N);

  // ---- edge head: 256 pairs per 512-thread block ----
  k_edge_head<<<(P + 255) / 256, 512, 0, stream>>>(B, ep, M1, mb1, M2, mb2, out, P);
}

// Round 10
// 457.861 us; speedup vs baseline: 1.2798x; 1.2798x over previous
//
#include <hip/hip_runtime.h>
#include <math.h>

// ---------------------------------------------------------------------------
// N2V GCN edge model, fp32.
//   CSR build: cnt=indeg(dst); dinv=rsqrt(cnt+1); rp=exscan; srcs+coefs bucketed
//   L1: A = x@W1 ; B = relu(gatherCSR(A) + A*dinv^2 + b1)
//   L2: A = B@W2 ; B = relu(gatherCSR(A) + A*dinv^2 + b2)
//   head: per pair: feat=[u,v,|u-v|,u*v]; z=relu(feat@M1+mb1); out=z@M2+mb2
// Round-10: revert head to round-8 (round-9's LDS-M1 variant spilled its
// per-t weight arrays to scratch: WRITE_SIZE 2->279MB, 1M bank conflicts,
// 294us). Head plateau ~181us accepted (issue-mix bound, ~1.7x FLOP floor).
// Gather: 2x manual unroll, both row loads issued before FMAs -> 2 in-flight
// L3 gathers per 16-lane group (latency hiding on the avg-degree-12 loop).
// ---------------------------------------------------------------------------

__global__ void k_count_int(const int* __restrict__ dst, int* __restrict__ cnt, int e) {
  int i = blockIdx.x * blockDim.x + threadIdx.x;
  if (i < e) atomicAdd(&cnt[dst[i]], 1);
}

__global__ void k_dinv(const int* __restrict__ cnt, float* __restrict__ dinv, int n) {
  int i = blockIdx.x * blockDim.x + threadIdx.x;
  if (i < n) dinv[i] = rsqrtf((float)cnt[i] + 1.0f);  // self-loop included
}

__global__ __launch_bounds__(256) void k_scan_block(const int* __restrict__ cnt,
                                                    int* __restrict__ rp,
                                                    int* __restrict__ bsum, int n) {
  __shared__ int wsum[4];
  int tid = threadIdx.x;
  int lane = tid & 63, w = tid >> 6;
  int idx = blockIdx.x * 1024 + tid * 4;
  int v0 = (idx + 0 < n) ? cnt[idx + 0] : 0;
  int v1 = (idx + 1 < n) ? cnt[idx + 1] : 0;
  int v2 = (idx + 2 < n) ? cnt[idx + 2] : 0;
  int v3 = (idx + 3 < n) ? cnt[idx + 3] : 0;
  int tot = v0 + v1 + v2 + v3;
  int x = tot;
#pragma unroll
  for (int off = 1; off < 64; off <<= 1) {
    int y = __shfl_up(x, off, 64);
    if (lane >= off) x += y;
  }
  if (lane == 63) wsum[w] = x;
  __syncthreads();
  int woff = 0;
  for (int i = 0; i < w; ++i) woff += wsum[i];
  int run = woff + x - tot;
  if (idx + 0 < n) rp[idx + 0] = run; run += v0;
  if (idx + 1 < n) rp[idx + 1] = run; run += v1;
  if (idx + 2 < n) rp[idx + 2] = run; run += v2;
  if (idx + 3 < n) rp[idx + 3] = run;
  if (tid == 255) bsum[blockIdx.x] = wsum[0] + wsum[1] + wsum[2] + wsum[3];
}

__global__ void k_scan_bsum(int* __restrict__ bsum, int nb) {
  int l = threadIdx.x;
  int v0 = (l < nb) ? bsum[l] : 0;
  int v1 = (64 + l < nb) ? bsum[64 + l] : 0;
  int i0 = v0;
#pragma unroll
  for (int off = 1; off < 64; off <<= 1) {
    int y = __shfl_up(i0, off, 64);
    if (l >= off) i0 += y;
  }
  int T0 = __shfl(i0, 63, 64);
  int i1 = v1;
#pragma unroll
  for (int off = 1; off < 64; off <<= 1) {
    int y = __shfl_up(i1, off, 64);
    if (l >= off) i1 += y;
  }
  if (l < nb) bsum[l] = i0 - v0;
  if (64 + l < nb) bsum[64 + l] = T0 + i1 - v1;
}

// add block offsets; also emit cursor copy for k_fill; set rp[n]=E.
__global__ void k_scan_add(int* __restrict__ rp, int* __restrict__ cur,
                           const int* __restrict__ bsum, int n, int e) {
  int i = blockIdx.x * blockDim.x + threadIdx.x;
  if (i < n) {
    int v = rp[i] + bsum[i >> 10];
    rp[i] = v;
    cur[i] = v;
  }
  if (i == 0) rp[n] = e;
}

// fill CSR buckets; also precompute per-edge coefficient.
__global__ void k_fill(const int* __restrict__ src, const int* __restrict__ dst,
                       int* __restrict__ cur, const float* __restrict__ dinv,
                       int* __restrict__ srcs, float* __restrict__ coefs, int e) {
  int i = blockIdx.x * blockDim.x + threadIdx.x;
  if (i >= e) return;
  int s = src[i], d = dst[i];
  int pos = atomicAdd(&cur[d], 1);
  srcs[pos] = s;
  coefs[pos] = dinv[s] * dinv[d];
}

// ---------------------------------------------------------------------------
// Matmul, W-in-VGPR: OUT[node][lane] = sum_k IN[node][k]*W[k][lane].
// Wave holds its W column in wreg[K] (loaded once). Node row staged per-lane
// coalesced -> LDS slice -> broadcast ds_read_b128 (4 k per read, 4 FMA each).
// Next row prefetched into regs under current node's compute.
// ---------------------------------------------------------------------------
template <int K>
__global__ __launch_bounds__(256) void k_matmul_w(const float* __restrict__ IN,
                                                  const float* __restrict__ W,
                                                  float* __restrict__ OUT,
                                                  int n, int npw) {
  __shared__ float rows[4][K];
  const int wv = threadIdx.x >> 6, lane = threadIdx.x & 63;
  float wreg[K];
#pragma unroll
  for (int k = 0; k < K; ++k) wreg[k] = W[k * 64 + lane];
  int base = (blockIdx.x * 4 + wv) * npw;
  if (base >= n) return;
  int nEnd = base + npw;
  if (nEnd > n) nEnd = n;
  float p0 = IN[(size_t)base * K + lane];
  float p1 = (K == 128) ? IN[(size_t)base * K + 64 + lane] : 0.f;
  for (int node = base; node < nEnd; ++node) {
    rows[wv][lane] = p0;
    if (K == 128) rows[wv][64 + lane] = p1;
    if (node + 1 < nEnd) {  // prefetch next row under this node's compute
      p0 = IN[(size_t)(node + 1) * K + lane];
      if (K == 128) p1 = IN[(size_t)(node + 1) * K + 64 + lane];
    }
    float a0 = 0.f, a1 = 0.f, a2 = 0.f, a3 = 0.f;
#pragma unroll
    for (int k = 0; k < K; k += 4) {
      float4 xk = *(const float4*)&rows[wv][k];
      a0 = fmaf(xk.x, wreg[k + 0], a0);
      a1 = fmaf(xk.y, wreg[k + 1], a1);
      a2 = fmaf(xk.z, wreg[k + 2], a2);
      a3 = fmaf(xk.w, wreg[k + 3], a3);
    }
    OUT[(size_t)node * 64 + lane] = (a0 + a1) + (a2 + a3);
  }
}

// one wave per node; wave-uniform shfl-broadcast accumulate; coalesced
// srcs/coefs streams. 2x unroll with both row loads issued before FMAs ->
// 2 in-flight gathers per 16-lane group.
__global__ void k_gather(const float* __restrict__ hlin, const int* __restrict__ rp,
                         const int* __restrict__ srcs, const float* __restrict__ coefs,
                         const float* __restrict__ dinv,
                         const float* __restrict__ bias, float* __restrict__ outB,
                         int n) {
  int warp = threadIdx.x >> 6, lane = threadIdx.x & 63;
  int node = blockIdx.x * 4 + warp;
  if (node >= n) return;
  int g = lane >> 4, l16 = lane & 15;
  int beg = rp[node], end = rp[node + 1];
  int deg = end - beg;
  float dn = dinv[node];
  float ax = 0.f, ay = 0.f, az = 0.f, aw = 0.f;
  for (int base = 0; base < deg; base += 64) {
    int rem = deg - base;
    int m = rem < 64 ? rem : 64;
    int idx = 0;
    float cf = 0.f;
    if (lane < m) {
      idx = srcs[beg + base + lane];
      cf = coefs[beg + base + lane];
    }
    int iters = (m + 3) >> 2;  // wave-uniform trip count
    int i = 0;
    for (; i + 2 <= iters; i += 2) {
      int k0 = g + 4 * i, k1 = k0 + 4;       // both <= 63
      int s0 = __shfl(idx, k0, 64);
      float c0 = __shfl(cf, k0, 64);
      int s1 = __shfl(idx, k1, 64);
      float c1 = __shfl(cf, k1, 64);
      float4 h0 = *(const float4*)(hlin + (size_t)s0 * 64 + l16 * 4);
      float4 h1 = *(const float4*)(hlin + (size_t)s1 * 64 + l16 * 4);
      ax = fmaf(h0.x, c0, ax);
      ay = fmaf(h0.y, c0, ay);
      az = fmaf(h0.z, c0, az);
      aw = fmaf(h0.w, c0, aw);
      ax = fmaf(h1.x, c1, ax);
      ay = fmaf(h1.y, c1, ay);
      az = fmaf(h1.z, c1, az);
      aw = fmaf(h1.w, c1, aw);
    }
    if (i < iters) {
      int k = g + 4 * i;
      int s = __shfl(idx, k, 64);
      float c = __shfl(cf, k, 64);
      float4 h = *(const float4*)(hlin + (size_t)s * 64 + l16 * 4);
      ax = fmaf(h.x, c, ax);
      ay = fmaf(h.y, c, ay);
      az = fmaf(h.z, c, az);
      aw = fmaf(h.w, c, aw);
    }
  }
#pragma unroll
  for (int off = 16; off < 64; off <<= 1) {
    ax += __shfl_xor(ax, off, 64);
    ay += __shfl_xor(ay, off, 64);
    az += __shfl_xor(az, off, 64);
    aw += __shfl_xor(aw, off, 64);
  }
  if (g == 0) {
    float4 hs = *(const float4*)(hlin + (size_t)node * 64 + l16 * 4);
    float4 bb = *(const float4*)(bias + l16 * 4);
    float dd = dn * dn;
    float4 o;
    o.x = ax + hs.x * dd + bb.x;
    o.y = ay + hs.y * dd + bb.y;
    o.z = az + hs.z * dd + bb.z;
    o.w = aw + hs.w * dd + bb.w;
    o.x = o.x > 0.f ? o.x : 0.f;
    o.y = o.y > 0.f ? o.y : 0.f;
    o.z = o.z > 0.f ? o.z : 0.f;
    o.w = o.w > 0.f ? o.w : 0.f;
    *(float4*)(outB + (size_t)node * 64 + l16 * 4) = o;
  }
}

// ---------------------------------------------------------------------------
// Edge head (round-8 version): 512 threads = 8 waves, 256 pairs/block,
// 4 pairs/lane. Wave w owns cols [8w, 8w+8); lane owns pairs 4*lane..+3.
// 4 phases x 16 rows; u[16][256] + v[16][256], parts reuse u -> 32KB LDS.
// Staging at 128B-line granularity: even phase loads the full line, stashes
// half in regs; odd phase is pure LDS writes.
// ---------------------------------------------------------------------------
__global__ __launch_bounds__(512, 6) void k_edge_head(
    const float* __restrict__ H, const int* __restrict__ ep,
    const float* __restrict__ M1, const float* __restrict__ mb1,
    const float* __restrict__ M2, const float* __restrict__ mb2,
    float* __restrict__ out, int p_total) {
  __shared__ float sbuf[8192];  // u:[0,4096) v:[4096,8192); parts reuse u

  const int tid = threadIdx.x;
  const int pair0 = blockIdx.x * 256;

  // staging identity: thread handles u (hf=0) or v (hf=1) of pair pi
  const int pi = tid & 255;
  const int hf = tid >> 8;
  const int gp_pi = pair0 + pi;
  const bool valid = gp_pi < p_total;
  int node = 0;
  if (valid) node = hf ? ep[p_total + gp_pi] : ep[gp_pi];
  float* __restrict__ myb = sbuf + hf * 4096;

  // gemm identity
  const int lane = tid & 63;
  const int w = tid >> 6;  // 0..7
  const int cg = __builtin_amdgcn_readfirstlane(w);
  const int p0 = 4 * lane;

  float acc[8][4];
#pragma unroll
  for (int c = 0; c < 8; ++c)
#pragma unroll
    for (int p = 0; p < 4; ++p) acc[c][p] = 0.f;

  float4 st0, st1, st2, st3;  // stash: next phase's 16 rows (64B)

#pragma unroll
  for (int ph = 0; ph < 4; ++ph) {
    if (ph) __syncthreads();  // previous phase fully consumed
    // ---- stage 16 rows of this thread's matrix (u or v), pair pi
    if (valid) {
      float4 c0, c1, c2, c3;
      if ((ph & 1) == 0) {
        // even phase: read the full 128B line (this phase + next phase)
        const float4* hr = (const float4*)(H + (size_t)node * 64 + ph * 16);
        c0 = hr[0]; c1 = hr[1]; c2 = hr[2]; c3 = hr[3];
        st0 = hr[4]; st1 = hr[5]; st2 = hr[6]; st3 = hr[7];
      } else {
        // odd phase: no global loads, use the stash
        c0 = st0; c1 = st1; c2 = st2; c3 = st3;
      }
      myb[0 * 256 + pi]  = c0.x; myb[1 * 256 + pi]  = c0.y;
      myb[2 * 256 + pi]  = c0.z; myb[3 * 256 + pi]  = c0.w;
      myb[4 * 256 + pi]  = c1.x; myb[5 * 256 + pi]  = c1.y;
      myb[6 * 256 + pi]  = c1.z; myb[7 * 256 + pi]  = c1.w;
      myb[8 * 256 + pi]  = c2.x; myb[9 * 256 + pi]  = c2.y;
      myb[10 * 256 + pi] = c2.z; myb[11 * 256 + pi] = c2.w;
      myb[12 * 256 + pi] = c3.x; myb[13 * 256 + pi] = c3.y;
      myb[14 * 256 + pi] = c3.z; myb[15 * 256 + pi] = c3.w;
    } else {
#pragma unroll
      for (int j = 0; j < 16; ++j) myb[j * 256 + pi] = 0.f;
    }
    __syncthreads();

    // ---- GEMM over this phase's 16 feature rows
#pragma unroll 2
    for (int t = 0; t < 16; ++t) {
      float4 u4 = *(const float4*)&sbuf[t * 256 + p0];
      float4 v4 = *(const float4*)&sbuf[4096 + t * 256 + p0];
      float uu[4] = {u4.x, u4.y, u4.z, u4.w};
      float vv[4] = {v4.x, v4.y, v4.z, v4.w};
      float dd[4], mm[4];
#pragma unroll
      for (int p = 0; p < 4; ++p) {
        dd[p] = fabsf(uu[p] - vv[p]);
        mm[p] = uu[p] * vv[p];
      }
      const int tt = ph * 16 + t;
      const float* r0 = M1 + (size_t)tt * 64 + cg * 8;   // u block
      const float* r1 = r0 + 64 * 64;                    // v block
      const float* r2 = r0 + 128 * 64;                   // |u-v| block
      const float* r3 = r0 + 192 * 64;                   // u*v block
#pragma unroll
      for (int c = 0; c < 8; ++c) {
        float w0 = r0[c], w1 = r1[c], w2 = r2[c], w3 = r3[c];
#pragma unroll
        for (int p = 0; p < 4; ++p) {
          acc[c][p] = fmaf(uu[p], w0, acc[c][p]);
          acc[c][p] = fmaf(vv[p], w1, acc[c][p]);
          acc[c][p] = fmaf(dd[p], w2, acc[c][p]);
          acc[c][p] = fmaf(mm[p], w3, acc[c][p]);
        }
      }
    }
  }

  __syncthreads();  // all reads of sbuf done; reuse u region for partials

  // epilogue: per pair p: part = sum_c relu(acc+mb1)*M2 over this wave's 8 cols
#pragma unroll
  for (int p = 0; p < 4; ++p) {
    float part = 0.f;
#pragma unroll
    for (int c = 0; c < 8; ++c) {
      float z = acc[c][p] + mb1[cg * 8 + c];
      z = z > 0.f ? z : 0.f;
      part = fmaf(z, M2[cg * 8 + c], part);
    }
    sbuf[w * 256 + p0 + p] = part;
  }
  __syncthreads();

  if (tid < 256) {
    int gp = pair0 + tid;
    if (gp < p_total) {
      float s = 0.f;
#pragma unroll
      for (int w8 = 0; w8 < 8; ++w8) s += sbuf[w8 * 256 + tid];
      out[gp] = s + mb2[0];
    }
  }
}

extern "C" void kernel_launch(void* const* d_in, const int* in_sizes, int n_in,
                              void* d_out, int out_size, void* d_ws, size_t ws_size,
                              hipStream_t stream) {
  const float* x   = (const float*)d_in[0];
  const int*   gei = (const int*)d_in[1];
  const int*   ep  = (const int*)d_in[2];
  const float* W1  = (const float*)d_in[3];
  const float* b1  = (const float*)d_in[4];
  const float* W2  = (const float*)d_in[5];
  const float* b2  = (const float*)d_in[6];
  const float* M1  = (const float*)d_in[7];
  const float* mb1 = (const float*)d_in[8];
  const float* M2  = (const float*)d_in[9];
  const float* mb2 = (const float*)d_in[10];
  float* out = (float*)d_out;

  const int N = in_sizes[0] / 128;
  const int E = in_sizes[1] / 2;
  const int P = in_sizes[2] / 2;
  const int* src = gei;
  const int* dst = gei + E;

  char* ws = (char*)d_ws;
  auto align256 = [](size_t b) { return (b + 255) & ~(size_t)255; };
  size_t degBytes  = align256((size_t)N * 4);
  size_t hBytes    = align256((size_t)N * 64 * 4);
  size_t cntBytes  = align256((size_t)N * 4);
  size_t rpBytes   = align256((size_t)(N + 1) * 4);
  size_t srcBytes  = align256((size_t)E * 4);

  size_t off = 0;
  float* dinv  = (float*)(ws + off); off += degBytes;
  float* A     = (float*)(ws + off); off += hBytes;    // N x 64 (hlin)
  float* B     = (float*)(ws + off); off += hBytes;    // N x 64 (h out)
  int*   cnt   = (int*)(ws + off);   off += cntBytes;  // counts -> cursors
  int*   rp    = (int*)(ws + off);   off += rpBytes;   // N+1
  int*   srcs  = (int*)(ws + off);   off += srcBytes;  // E
  float* coefs = (float*)(ws + off); off += srcBytes;  // E
  int*   bsum  = (int*)(ws + off);                     // 128

  const int BLK = 256;
  const int nb = (N + 1023) / 1024;  // scan blocks; <=128 supported (N<=131072)

  // ---- CSR build + normalization ----
  hipMemsetAsync(cnt, 0, (size_t)N * 4, stream);
  k_count_int<<<(E + BLK - 1) / BLK, BLK, 0, stream>>>(dst, cnt, E);
  k_dinv<<<(N + BLK - 1) / BLK, BLK, 0, stream>>>(cnt, dinv, N);
  k_scan_block<<<nb, BLK, 0, stream>>>(cnt, rp, bsum, N);
  k_scan_bsum<<<1, 64, 0, stream>>>(bsum, nb);
  k_scan_add<<<(N + BLK - 1) / BLK, BLK, 0, stream>>>(rp, cnt, bsum, N, E);
  k_fill<<<(E + BLK - 1) / BLK, BLK, 0, stream>>>(src, dst, cnt, dinv, srcs, coefs, E);

  const int NPW = 16;  // nodes per wave in k_matmul_w
  const int mmGrid = (N + 4 * NPW - 1) / (4 * NPW);

  // ---- layer 1 ----
  k_matmul_w<128><<<mmGrid, BLK, 0, stream>>>(x, W1, A, N, NPW);
  k_gather<<<(N + 3) / 4, BLK, 0, stream>>>(A, rp, srcs, coefs, dinv, b1, B, N);

  // ---- layer 2 ----
  k_matmul_w<64><<<mmGrid, BLK, 0, stream>>>(B, W2, A, N, NPW);
  k_gather<<<(N + 3) / 4, BLK, 0, stream>>>(A, rp, srcs, coefs, dinv, b2, B, N);

  // ---- edge head: 256 pairs per 512-thread block ----
  k_edge_head<<<(P + 255) / 256, 512, 0, stream>>>(B, ep, M1, mb1, M2, mb2, out, P);
}